// Round 19
// baseline (75.843 us; speedup 1.0000x reference)
//
#include <hip/hip_runtime.h>
#include <hip/hip_bf16.h>

#define NSTATES 8
#define HD      1024
#define NBATCH  16384
#define NT      16      // K-tiles of 64

// output layout (flat fp32, return order)
#define OUT_MEAS 0
#define OUT_CP   16777216
#define OUT_ENT  16777224
#define OUT_COH  16777225
#define OUT_AD   16777226
#define OUT_PH   16785418

typedef __attribute__((ext_vector_type(8))) short short8;
typedef __attribute__((ext_vector_type(4))) float f32x4;

__device__ __forceinline__ short f2bf(float f) {
    union { float f; unsigned u; } x; x.f = f;
    unsigned r = x.u + 0x7fffu + ((x.u >> 16) & 1u);  // RNE
    return (short)(r >> 16);
}

__device__ __forceinline__ unsigned cvtpk(float lo, float hi) {
    unsigned r;
    asm("v_cvt_pk_bf16_f32 %0, %1, %2" : "=v"(r) : "v"(lo), "v"(hi));
    return r;
}

__device__ __forceinline__ short8 pack8pk(float4 a, float4 b) {
    union { unsigned u[4]; short8 s; } r;
    r.u[0] = cvtpk(a.x, a.y);
    r.u[1] = cvtpk(a.z, a.w);
    r.u[2] = cvtpk(b.x, b.y);
    r.u[3] = cvtpk(b.z, b.w);
    return r.s;
}

// ---------------- K1: amplitude pipeline (1 block, 1024 threads) ----------------
__global__ __launch_bounds__(1024) void k_amps(const float* __restrict__ AR,
                                               const float* __restrict__ AI,
                                               const float* __restrict__ H,
                                               float* __restrict__ out,
                                               float* __restrict__ w) {
    __shared__ float redA[16 * NSTATES];
    __shared__ float redB[16 * 10];
    __shared__ float norms[NSTATES];
    __shared__ float sA[8][8], sA2[8][8], sA3[8][8];
    __shared__ float Ur[8][8], Ui[8][8];
    __shared__ float lamsa[2];

    const int tid = threadIdx.x;
    const int lane = tid & 63, wid = tid >> 6;
    const int d = tid;

    float arv[NSTATES], aiv[NSTATES];
    #pragma unroll
    for (int s = 0; s < NSTATES; s++) {
        arv[s] = AR[s * HD + d];
        aiv[s] = AI[s * HD + d];
    }
    float p[NSTATES];
    #pragma unroll
    for (int s = 0; s < NSTATES; s++) p[s] = arv[s] * arv[s] + aiv[s] * aiv[s];
    #pragma unroll
    for (int s = 0; s < NSTATES; s++)
        #pragma unroll
        for (int o = 32; o > 0; o >>= 1) p[s] += __shfl_down(p[s], o, 64);
    if (lane == 0)
        #pragma unroll
        for (int s = 0; s < NSTATES; s++) redA[wid * NSTATES + s] = p[s];
    if (tid < 64) {
        int i = tid >> 3, j = tid & 7;
        sA[i][j] = 0.5f * (H[i * 8 + j] + H[j * 8 + i]) * 0.01f;  // DT/PLANCK
    }
    __syncthreads();
    if (tid < 8) {
        float acc = 0.f;
        #pragma unroll
        for (int v = 0; v < 16; v++) acc += redA[v * NSTATES + tid];
        norms[tid] = acc;
    }
    if (tid < 64) {
        int i = tid >> 3, j = tid & 7;
        float acc = 0.f;
        #pragma unroll
        for (int k = 0; k < 8; k++) acc += sA[i][k] * sA[k][j];
        sA2[i][j] = acc;
    }
    __syncthreads();
    if (tid < 64) {
        int i = tid >> 3, j = tid & 7;
        float acc = 0.f;
        #pragma unroll
        for (int k = 0; k < 8; k++) acc += sA2[i][k] * sA[k][j];
        sA3[i][j] = acc;
        Ur[i][j] = ((i == j) ? 1.f : 0.f) - 0.5f * sA2[i][j];   // cos(A)
        Ui[i][j] = -(sA[i][j] - sA3[i][j] * (1.f / 6.f));       // -sin(A)
    }
    __syncthreads();

    #pragma unroll
    for (int s = 0; s < NSTATES; s++) {
        float inv = 1.0f / sqrtf(norms[s] + 1e-8f);
        arv[s] *= inv;
        aiv[s] *= inv;
    }
    float nr[NSTATES], ni[NSTATES];
    #pragma unroll
    for (int s = 0; s < NSTATES; s++) {
        float xr = 0.f, xi = 0.f;
        #pragma unroll
        for (int t = 0; t < NSTATES; t++) {
            float ur = Ur[s][t], ui = Ui[s][t];
            xr += ur * arv[t] - ui * aiv[t];
            xi += ur * aiv[t] + ui * arv[t];
        }
        nr[s] = xr; ni[s] = xi;
    }
    float dist[NSTATES], csum = 0.f, sabs = 0.f;
    #pragma unroll
    for (int s = 0; s < NSTATES; s++) {
        dist[s] = nr[s] * nr[s] + ni[s] * ni[s];
        csum += dist[s];
        sabs += sqrtf(dist[s]);
    }
    #pragma unroll
    for (int s = 0; s < NSTATES; s++) {
        out[OUT_AD + s * HD + d] = dist[s];
        out[OUT_PH + s * HD + d] = atan2f(ni[s], nr[s]);
        w[s * HD + d] = nr[s];
    }
    float cinv = 1.0f / (csum + 1e-8f);
    float q[10];
    #pragma unroll
    for (int s = 0; s < NSTATES; s++) q[s] = dist[s] * cinv;
    q[8] = csum; q[9] = sabs;
    #pragma unroll
    for (int v = 0; v < 10; v++)
        #pragma unroll
        for (int o = 32; o > 0; o >>= 1) q[v] += __shfl_down(q[v], o, 64);
    if (lane == 0)
        #pragma unroll
        for (int v = 0; v < 10; v++) redB[wid * 10 + v] = q[v];
    __syncthreads();
    if (tid < 10) {
        float acc = 0.f;
        #pragma unroll
        for (int v = 0; v < 16; v++) acc += redB[v * 10 + tid];
        if (tid < 8)       out[OUT_CP + tid] = acc * (1.0f / HD);
        else               lamsa[tid - 8] = acc;
    }
    __syncthreads();
    if (tid == 0) {
        float lam = lamsa[0], sa = lamsa[1];
        out[OUT_ENT] = -(lam * logf(lam + 1e-12f));
        out[OUT_COH] = sa * sa - lam;
    }
}

// ------- K3: fused project + transpose: Mt[e,d] = bf16( sum_s w[s,e]*P[s,d,e] ) -
__global__ __launch_bounds__(256) void k_project_t(const float* __restrict__ P,
                                                   const float* __restrict__ w,
                                                   short* __restrict__ Mt) {
    __shared__ float tile[64][65];
    int d0 = (blockIdx.x >> 4) * 64;
    int e0 = (blockIdx.x & 15) * 64;
    int tx = threadIdx.x & 63, ty = threadIdx.x >> 6;
    float wv[NSTATES];
    #pragma unroll
    for (int s = 0; s < NSTATES; s++) wv[s] = w[s * HD + e0 + tx];
    #pragma unroll
    for (int j = 0; j < 16; j++) {
        int r = ty + 4 * j;
        float acc = 0.f;
        #pragma unroll
        for (int s = 0; s < NSTATES; s++)
            acc += wv[s] * P[(size_t)s * HD * HD + (size_t)(d0 + r) * HD + e0 + tx];
        tile[r][tx] = acc;
    }
    __syncthreads();
    #pragma unroll
    for (int j = 0; j < 16; j++) {
        int er = ty + 4 * j;
        Mt[(size_t)(e0 + er) * HD + d0 + tx] = f2bf(tile[tx][er]);
    }
}

// -------- K4: out = bf16(X) @ Mt^T -- JIT-A 3-phase lookahead + peeled last tile
// R17 verbatim EXCEPT C-stores are non-temporal (nt): C is write-once and >> L2,
// so skipping L2 allocation preserves X/Mt residency for co-XCD blocks.

__device__ __forceinline__ void stage_half_B(const short* __restrict__ srcBase,
                                             int rowbase, int h, int t2,
                                             short* dst, const int* goff,
                                             const int* ldsoff) {
    #pragma unroll
    for (int i = 0; i < 2; i++) {
        const short* g = srcBase + (size_t)(rowbase + h * 128) * HD + t2 * 64 + goff[i];
        __builtin_amdgcn_global_load_lds(
            (const __attribute__((address_space(1))) void*)g,
            (__attribute__((address_space(3))) void*)(dst + h * 8192 + ldsoff[i]),
            16, 0, 0);
    }
}

#define XLOAD(dst, h, t2)                                                      \
    {                                                                          \
        const float* b_ = X + (size_t)(brow + (h) * 128) * HD + (t2) * 64;     \
        dst[0] = *reinterpret_cast<const float4*>(b_ + goff[0]);               \
        dst[1] = *reinterpret_cast<const float4*>(b_ + goff[0] + 4);           \
        dst[2] = *reinterpret_cast<const float4*>(b_ + goff[1]);               \
        dst[3] = *reinterpret_cast<const float4*>(b_ + goff[1] + 4);           \
    }

#define XWRITE(dstlds, src)                                                    \
    {                                                                          \
        *reinterpret_cast<short8*>((dstlds) + ldsoff[0]) = pack8pk(src[0], src[1]); \
        *reinterpret_cast<short8*>((dstlds) + ldsoff[1]) = pack8pk(src[2], src[3]); \
    }

#define LOAD_A(qa)                                                             \
    _Pragma("unroll") for (int mf = 0; mf < 4; mf++)                           \
    _Pragma("unroll") for (int kk = 0; kk < 2; kk++)                           \
        af[mf][kk] = *reinterpret_cast<const short8*>(                         \
            &Acur[((qa) * 128 + wr64 + mf * 16 + ln15) * 64 + kx[kk]]);

#define LOAD_B_TO(dst, qb)                                                     \
    _Pragma("unroll") for (int nf = 0; nf < 2; nf++)                           \
    _Pragma("unroll") for (int kk = 0; kk < 2; kk++)                           \
        dst[nf][kk] = *reinterpret_cast<const short8*>(                        \
            &Bcur[((qb) * 128 + wn32 + nf * 16 + ln15) * 64 + kx[kk]]);

#define MFMA_P(qa, qb, breg)                                                   \
    _Pragma("unroll") for (int mf = 0; mf < 4; mf++)                           \
    _Pragma("unroll") for (int nf = 0; nf < 2; nf++)                           \
    _Pragma("unroll") for (int kk = 0; kk < 2; kk++)                           \
        acc[(qa) * 4 + mf][(qb) * 2 + nf] =                                    \
            __builtin_amdgcn_mfma_f32_16x16x32_bf16(                           \
                af[mf][kk], breg[nf][kk], acc[(qa) * 4 + mf][(qb) * 2 + nf], 0, 0, 0);

// store one C-quadrant, non-temporal (C/D layout col=lane&15, row=(lane>>4)*4+j)
#define STORE_Q(qa, qb)                                                        \
    _Pragma("unroll") for (int mf = 0; mf < 4; mf++)                           \
    _Pragma("unroll") for (int nf = 0; nf < 2; nf++)                           \
    _Pragma("unroll") for (int j = 0; j < 4; j++) {                            \
        int r = brow + (qa) * 128 + wr64 + mf * 16 + l16 * 4 + j;              \
        int c = bcol + (qb) * 128 + wn32 + nf * 16 + ln15;                     \
        __builtin_nontemporal_store(acc[(qa) * 4 + mf][(qb) * 2 + nf][j],      \
                                    &out[(size_t)r * HD + c]);                 \
    }

__global__ __launch_bounds__(512, 1) void k_gemm_jit3(const float* __restrict__ X,
                                                      const short* __restrict__ Mt,
                                                      float* __restrict__ out) {
    __shared__ short As[2][256 * 64];   // 64 KiB: [buf][half*128+row][kchunk]
    __shared__ short Bs[2][256 * 64];   // 64 KiB

    const int bid = blockIdx.x;                       // 256 blocks (64 bm x 4 bn)
    const int swz = (bid & 7) * 32 + (bid >> 3);      // XCD-contiguous, bijective
    const int brow = (swz >> 2) * 256;
    const int bcol = (swz & 3) * 256;

    const int tid  = threadIdx.x;
    const int lane = tid & 63, wid = tid >> 6;
    const int wr = wid >> 2, wn = wid & 3;
    const int ln15 = lane & 15, l16 = lane >> 4;
    const int wr64 = wr * 64;
    const int wn32 = wn * 32;

    // ds_read swizzled k-chunk offsets (shorts): chunk = kg ^ (row&7); row&7==ln15&7
    int kx[2];
    kx[0] = ((l16 + 0) ^ (ln15 & 7)) * 8;
    kx[1] = ((l16 + 4) ^ (ln15 & 7)) * 8;

    // staging offsets (elements): LDS linear dest, inverse-swizzled global source
    int goff[2], ldsoff[2];
    #pragma unroll
    for (int i = 0; i < 2; i++) {
        int c = tid + 512 * i;
        int row = c >> 3, kc = c & 7;
        goff[i]   = row * HD + ((kc ^ (row & 7)) * 8);
        ldsoff[i] = c * 8;
    }

    short* A0 = &As[0][0]; short* A1b = &As[1][0];
    short* B0 = &Bs[0][0]; short* B1b = &Bs[1][0];

    f32x4 acc[8][4];
    #pragma unroll
    for (int m = 0; m < 8; m++)
        #pragma unroll
        for (int n = 0; n < 4; n++) acc[m][n] = (f32x4){0.f, 0.f, 0.f, 0.f};

    float4 xrL[4], xrH[4];   // X windows: xrL = lo-half, xrH = hi-half

    // ---- prologue: A(0) via reg+write; B(0); B-hi(1); xrL <- lo(1) ----
    XLOAD(xrL, 0, 0);
    XLOAD(xrH, 1, 0);
    stage_half_B(Mt, bcol, 0, 0, B0, goff, ldsoff);
    stage_half_B(Mt, bcol, 1, 0, B0, goff, ldsoff);
    stage_half_B(Mt, bcol, 1, 1, B1b, goff, ldsoff);
    XWRITE(A0, xrL);            // implicit vmcnt drains X(0) loads
    XWRITE(A0 + 8192, xrH);
    XLOAD(xrL, 0, 1);           // lo(1), written at ph3(0)
    // outstanding: [B(0):4, B-hi(1):2, xrL:4]; need B(0) -> vmcnt(6);
    // lgkmcnt(0) publishes A0 writes.
    asm volatile("s_waitcnt vmcnt(6) lgkmcnt(0)" ::: "memory");
    __builtin_amdgcn_s_barrier();

    short8 af[4][2], bfL[2][2], bfH[2][2];

    #pragma unroll 1
    for (int t = 0; t < NT - 1; t++) {
        const int cur = t & 1;
        short* Acur  = cur ? A1b : A0;
        short* Bcur  = cur ? B1b : B0;
        short* Anext = cur ? A0 : A1b;   // buf of t+1
        short* Bnext = cur ? B0 : B1b;

        // ---- ph1: quadrant (0,0); issue X-hi(t+1) (3-phase lead to ph4)
        LOAD_A(0); LOAD_B_TO(bfL, 0);
        if (t + 1 < NT) XLOAD(xrH, 1, (t + 1));
        __builtin_amdgcn_s_barrier();
        __builtin_amdgcn_s_setprio(1);
        MFMA_P(0, 0, bfL);
        __builtin_amdgcn_s_setprio(0);

        // ---- ph2: quadrant (0,1); DMA B-lo(t+1)
        LOAD_B_TO(bfH, 1);
        if (t + 1 < NT) stage_half_B(Mt, bcol, 0, t + 1, Bnext, goff, ldsoff);
        __builtin_amdgcn_s_barrier();
        __builtin_amdgcn_s_setprio(1);
        MFMA_P(0, 1, bfH);
        __builtin_amdgcn_s_setprio(0);

        // ---- ph3: quadrant (1,1); write A-lo(t+1) from xrL (issued ph4(t-1))
        LOAD_A(1);
        if (t + 1 < NT) XWRITE(Anext, xrL);   // implicit vmcnt(2): leaves B-lo
        __builtin_amdgcn_s_barrier();
        __builtin_amdgcn_s_setprio(1);
        MFMA_P(1, 1, bfH);
        __builtin_amdgcn_s_setprio(0);

        // ---- ph4: quadrant (1,0) [read-free: bfL persists];
        //      write A-hi(t+1) from xrH (issued ph1(t)); issue X-lo(t+2);
        //      DMA B-hi(t+2) into cur freed slot
        if (t + 1 < NT) XWRITE(Anext + 8192, xrH);  // implicit vmcnt(2): drains xrH
        if (t + 2 < NT) {
            XLOAD(xrL, 0, (t + 2));                 // 3-phase lead to ph3(t+1)
            stage_half_B(Mt, bcol, 1, t + 2, Bcur, goff, ldsoff);
        }
        // outstanding: [B-lo(t+1):2, xrL(t+2):4, B-hi(t+2):2] = 8;
        // vmcnt(6) drains B-lo(t+1); lgkmcnt(0) publishes both A-half writes.
        if (t + 2 < NT)      asm volatile("s_waitcnt vmcnt(6) lgkmcnt(0)" ::: "memory");
        else if (t + 1 < NT) asm volatile("s_waitcnt vmcnt(0) lgkmcnt(0)" ::: "memory");
        __builtin_amdgcn_s_barrier();
        __builtin_amdgcn_s_setprio(1);
        MFMA_P(1, 0, bfL);
        __builtin_amdgcn_s_setprio(0);
    }

    // ---- peeled tile NT-1 (cur=1): all data resident; distribute C stores ----
    {
        short* Acur = A1b;
        short* Bcur = B1b;

        // ph1: quadrant (0,0) -> store it
        LOAD_A(0); LOAD_B_TO(bfL, 0);
        __builtin_amdgcn_s_setprio(1);
        MFMA_P(0, 0, bfL);
        __builtin_amdgcn_s_setprio(0);
        STORE_Q(0, 0);

        // ph2: quadrant (0,1) -> store it
        LOAD_B_TO(bfH, 1);
        __builtin_amdgcn_s_setprio(1);
        MFMA_P(0, 1, bfH);
        __builtin_amdgcn_s_setprio(0);
        STORE_Q(0, 1);

        // ph3: quadrant (1,1) -> store it
        LOAD_A(1);
        __builtin_amdgcn_s_setprio(1);
        MFMA_P(1, 1, bfH);
        __builtin_amdgcn_s_setprio(0);
        STORE_Q(1, 1);

        // ph4: quadrant (1,0) -> store it
        __builtin_amdgcn_s_setprio(1);
        MFMA_P(1, 0, bfL);
        __builtin_amdgcn_s_setprio(0);
        STORE_Q(1, 0);
    }
}

extern "C" void kernel_launch(void* const* d_in, const int* in_sizes, int n_in,
                              void* d_out, int out_size, void* d_ws, size_t ws_size,
                              hipStream_t stream) {
    const float* X  = (const float*)d_in[0];  // [16384,1024]
    const float* AR = (const float*)d_in[1];
    const float* AI = (const float*)d_in[2];
    const float* H  = (const float*)d_in[3];
    const float* P  = (const float*)d_in[4];  // [8,1024,1024]
    float* out = (float*)d_out;

    char* ws = (char*)d_ws;
    float* w  = (float*)ws;                       // 32 KB
    short* Mt = (short*)(ws + 32768);             // 2 MB  (bf16 M^T)

    k_amps<<<1, 1024, 0, stream>>>(AR, AI, H, out, w);
    k_project_t<<<256, 256, 0, stream>>>(P, w, Mt);
    k_gemm_jit3<<<(NBATCH / 256) * (HD / 256), 512, 0, stream>>>(X, Mt, out);
}

// Round 20
// 69.453 us; speedup vs baseline: 1.0920x; 1.0920x over previous
//
#include <hip/hip_runtime.h>
#include <hip/hip_bf16.h>

#define NSTATES 8
#define HD      1024
#define NBATCH  16384
#define NT      16      // K-tiles of 64

// output layout (flat fp32, return order)
#define OUT_MEAS 0
#define OUT_CP   16777216
#define OUT_ENT  16777224
#define OUT_COH  16777225
#define OUT_AD   16777226
#define OUT_PH   16785418

typedef __attribute__((ext_vector_type(8))) short short8;
typedef __attribute__((ext_vector_type(4))) float f32x4;

__device__ __forceinline__ short f2bf(float f) {
    union { float f; unsigned u; } x; x.f = f;
    unsigned r = x.u + 0x7fffu + ((x.u >> 16) & 1u);  // RNE
    return (short)(r >> 16);
}

__device__ __forceinline__ unsigned cvtpk(float lo, float hi) {
    unsigned r;
    asm("v_cvt_pk_bf16_f32 %0, %1, %2" : "=v"(r) : "v"(lo), "v"(hi));
    return r;
}

__device__ __forceinline__ short8 pack8pk(float4 a, float4 b) {
    union { unsigned u[4]; short8 s; } r;
    r.u[0] = cvtpk(a.x, a.y);
    r.u[1] = cvtpk(a.z, a.w);
    r.u[2] = cvtpk(b.x, b.y);
    r.u[3] = cvtpk(b.z, b.w);
    return r.s;
}

// ---------------- K1: amplitude pipeline (1 block, 1024 threads) ----------------
__global__ __launch_bounds__(1024) void k_amps(const float* __restrict__ AR,
                                               const float* __restrict__ AI,
                                               const float* __restrict__ H,
                                               float* __restrict__ out,
                                               float* __restrict__ w) {
    __shared__ float redA[16 * NSTATES];
    __shared__ float redB[16 * 10];
    __shared__ float norms[NSTATES];
    __shared__ float sA[8][8], sA2[8][8], sA3[8][8];
    __shared__ float Ur[8][8], Ui[8][8];
    __shared__ float lamsa[2];

    const int tid = threadIdx.x;
    const int lane = tid & 63, wid = tid >> 6;
    const int d = tid;

    float arv[NSTATES], aiv[NSTATES];
    #pragma unroll
    for (int s = 0; s < NSTATES; s++) {
        arv[s] = AR[s * HD + d];
        aiv[s] = AI[s * HD + d];
    }
    float p[NSTATES];
    #pragma unroll
    for (int s = 0; s < NSTATES; s++) p[s] = arv[s] * arv[s] + aiv[s] * aiv[s];
    #pragma unroll
    for (int s = 0; s < NSTATES; s++)
        #pragma unroll
        for (int o = 32; o > 0; o >>= 1) p[s] += __shfl_down(p[s], o, 64);
    if (lane == 0)
        #pragma unroll
        for (int s = 0; s < NSTATES; s++) redA[wid * NSTATES + s] = p[s];
    if (tid < 64) {
        int i = tid >> 3, j = tid & 7;
        sA[i][j] = 0.5f * (H[i * 8 + j] + H[j * 8 + i]) * 0.01f;  // DT/PLANCK
    }
    __syncthreads();
    if (tid < 8) {
        float acc = 0.f;
        #pragma unroll
        for (int v = 0; v < 16; v++) acc += redA[v * NSTATES + tid];
        norms[tid] = acc;
    }
    if (tid < 64) {
        int i = tid >> 3, j = tid & 7;
        float acc = 0.f;
        #pragma unroll
        for (int k = 0; k < 8; k++) acc += sA[i][k] * sA[k][j];
        sA2[i][j] = acc;
    }
    __syncthreads();
    if (tid < 64) {
        int i = tid >> 3, j = tid & 7;
        float acc = 0.f;
        #pragma unroll
        for (int k = 0; k < 8; k++) acc += sA2[i][k] * sA[k][j];
        sA3[i][j] = acc;
        Ur[i][j] = ((i == j) ? 1.f : 0.f) - 0.5f * sA2[i][j];   // cos(A)
        Ui[i][j] = -(sA[i][j] - sA3[i][j] * (1.f / 6.f));       // -sin(A)
    }
    __syncthreads();

    #pragma unroll
    for (int s = 0; s < NSTATES; s++) {
        float inv = 1.0f / sqrtf(norms[s] + 1e-8f);
        arv[s] *= inv;
        aiv[s] *= inv;
    }
    float nr[NSTATES], ni[NSTATES];
    #pragma unroll
    for (int s = 0; s < NSTATES; s++) {
        float xr = 0.f, xi = 0.f;
        #pragma unroll
        for (int t = 0; t < NSTATES; t++) {
            float ur = Ur[s][t], ui = Ui[s][t];
            xr += ur * arv[t] - ui * aiv[t];
            xi += ur * aiv[t] + ui * arv[t];
        }
        nr[s] = xr; ni[s] = xi;
    }
    float dist[NSTATES], csum = 0.f, sabs = 0.f;
    #pragma unroll
    for (int s = 0; s < NSTATES; s++) {
        dist[s] = nr[s] * nr[s] + ni[s] * ni[s];
        csum += dist[s];
        sabs += sqrtf(dist[s]);
    }
    #pragma unroll
    for (int s = 0; s < NSTATES; s++) {
        out[OUT_AD + s * HD + d] = dist[s];
        out[OUT_PH + s * HD + d] = atan2f(ni[s], nr[s]);
        w[s * HD + d] = nr[s];
    }
    float cinv = 1.0f / (csum + 1e-8f);
    float q[10];
    #pragma unroll
    for (int s = 0; s < NSTATES; s++) q[s] = dist[s] * cinv;
    q[8] = csum; q[9] = sabs;
    #pragma unroll
    for (int v = 0; v < 10; v++)
        #pragma unroll
        for (int o = 32; o > 0; o >>= 1) q[v] += __shfl_down(q[v], o, 64);
    if (lane == 0)
        #pragma unroll
        for (int v = 0; v < 10; v++) redB[wid * 10 + v] = q[v];
    __syncthreads();
    if (tid < 10) {
        float acc = 0.f;
        #pragma unroll
        for (int v = 0; v < 16; v++) acc += redB[v * 10 + tid];
        if (tid < 8)       out[OUT_CP + tid] = acc * (1.0f / HD);
        else               lamsa[tid - 8] = acc;
    }
    __syncthreads();
    if (tid == 0) {
        float lam = lamsa[0], sa = lamsa[1];
        out[OUT_ENT] = -(lam * logf(lam + 1e-12f));
        out[OUT_COH] = sa * sa - lam;
    }
}

// ------- K3: fused project + transpose: Mt[e,d] = bf16( sum_s w[s,e]*P[s,d,e] ) -
__global__ __launch_bounds__(256) void k_project_t(const float* __restrict__ P,
                                                   const float* __restrict__ w,
                                                   short* __restrict__ Mt) {
    __shared__ float tile[64][65];
    int d0 = (blockIdx.x >> 4) * 64;
    int e0 = (blockIdx.x & 15) * 64;
    int tx = threadIdx.x & 63, ty = threadIdx.x >> 6;
    float wv[NSTATES];
    #pragma unroll
    for (int s = 0; s < NSTATES; s++) wv[s] = w[s * HD + e0 + tx];
    #pragma unroll
    for (int j = 0; j < 16; j++) {
        int r = ty + 4 * j;
        float acc = 0.f;
        #pragma unroll
        for (int s = 0; s < NSTATES; s++)
            acc += wv[s] * P[(size_t)s * HD * HD + (size_t)(d0 + r) * HD + e0 + tx];
        tile[r][tx] = acc;
    }
    __syncthreads();
    #pragma unroll
    for (int j = 0; j < 16; j++) {
        int er = ty + 4 * j;
        Mt[(size_t)(e0 + er) * HD + d0 + tx] = f2bf(tile[tx][er]);
    }
}

// -------- K4: out = bf16(X) @ Mt^T -- JIT-A 3-phase lookahead + peeled last tile
// (R17 exact: best-known configuration, 69.0 us total.)

__device__ __forceinline__ void stage_half_B(const short* __restrict__ srcBase,
                                             int rowbase, int h, int t2,
                                             short* dst, const int* goff,
                                             const int* ldsoff) {
    #pragma unroll
    for (int i = 0; i < 2; i++) {
        const short* g = srcBase + (size_t)(rowbase + h * 128) * HD + t2 * 64 + goff[i];
        __builtin_amdgcn_global_load_lds(
            (const __attribute__((address_space(1))) void*)g,
            (__attribute__((address_space(3))) void*)(dst + h * 8192 + ldsoff[i]),
            16, 0, 0);
    }
}

#define XLOAD(dst, h, t2)                                                      \
    {                                                                          \
        const float* b_ = X + (size_t)(brow + (h) * 128) * HD + (t2) * 64;     \
        dst[0] = *reinterpret_cast<const float4*>(b_ + goff[0]);               \
        dst[1] = *reinterpret_cast<const float4*>(b_ + goff[0] + 4);           \
        dst[2] = *reinterpret_cast<const float4*>(b_ + goff[1]);               \
        dst[3] = *reinterpret_cast<const float4*>(b_ + goff[1] + 4);           \
    }

#define XWRITE(dstlds, src)                                                    \
    {                                                                          \
        *reinterpret_cast<short8*>((dstlds) + ldsoff[0]) = pack8pk(src[0], src[1]); \
        *reinterpret_cast<short8*>((dstlds) + ldsoff[1]) = pack8pk(src[2], src[3]); \
    }

#define LOAD_A(qa)                                                             \
    _Pragma("unroll") for (int mf = 0; mf < 4; mf++)                           \
    _Pragma("unroll") for (int kk = 0; kk < 2; kk++)                           \
        af[mf][kk] = *reinterpret_cast<const short8*>(                         \
            &Acur[((qa) * 128 + wr64 + mf * 16 + ln15) * 64 + kx[kk]]);

#define LOAD_B_TO(dst, qb)                                                     \
    _Pragma("unroll") for (int nf = 0; nf < 2; nf++)                           \
    _Pragma("unroll") for (int kk = 0; kk < 2; kk++)                           \
        dst[nf][kk] = *reinterpret_cast<const short8*>(                        \
            &Bcur[((qb) * 128 + wn32 + nf * 16 + ln15) * 64 + kx[kk]]);

#define MFMA_P(qa, qb, breg)                                                   \
    _Pragma("unroll") for (int mf = 0; mf < 4; mf++)                           \
    _Pragma("unroll") for (int nf = 0; nf < 2; nf++)                           \
    _Pragma("unroll") for (int kk = 0; kk < 2; kk++)                           \
        acc[(qa) * 4 + mf][(qb) * 2 + nf] =                                    \
            __builtin_amdgcn_mfma_f32_16x16x32_bf16(                           \
                af[mf][kk], breg[nf][kk], acc[(qa) * 4 + mf][(qb) * 2 + nf], 0, 0, 0);

// store one C-quadrant (C/D layout col=lane&15, row=(lane>>4)*4+j  [m89])
#define STORE_Q(qa, qb)                                                        \
    _Pragma("unroll") for (int mf = 0; mf < 4; mf++)                           \
    _Pragma("unroll") for (int nf = 0; nf < 2; nf++)                           \
    _Pragma("unroll") for (int j = 0; j < 4; j++) {                            \
        int r = brow + (qa) * 128 + wr64 + mf * 16 + l16 * 4 + j;              \
        int c = bcol + (qb) * 128 + wn32 + nf * 16 + ln15;                     \
        out[(size_t)r * HD + c] = acc[(qa) * 4 + mf][(qb) * 2 + nf][j];        \
    }

__global__ __launch_bounds__(512, 1) void k_gemm_jit3(const float* __restrict__ X,
                                                      const short* __restrict__ Mt,
                                                      float* __restrict__ out) {
    __shared__ short As[2][256 * 64];   // 64 KiB: [buf][half*128+row][kchunk]
    __shared__ short Bs[2][256 * 64];   // 64 KiB

    const int bid = blockIdx.x;                       // 256 blocks (64 bm x 4 bn)
    const int swz = (bid & 7) * 32 + (bid >> 3);      // XCD-contiguous, bijective
    const int brow = (swz >> 2) * 256;
    const int bcol = (swz & 3) * 256;

    const int tid  = threadIdx.x;
    const int lane = tid & 63, wid = tid >> 6;
    const int wr = wid >> 2, wn = wid & 3;
    const int ln15 = lane & 15, l16 = lane >> 4;
    const int wr64 = wr * 64;
    const int wn32 = wn * 32;

    // ds_read swizzled k-chunk offsets (shorts): chunk = kg ^ (row&7); row&7==ln15&7
    int kx[2];
    kx[0] = ((l16 + 0) ^ (ln15 & 7)) * 8;
    kx[1] = ((l16 + 4) ^ (ln15 & 7)) * 8;

    // staging offsets (elements): LDS linear dest, inverse-swizzled global source
    int goff[2], ldsoff[2];
    #pragma unroll
    for (int i = 0; i < 2; i++) {
        int c = tid + 512 * i;
        int row = c >> 3, kc = c & 7;
        goff[i]   = row * HD + ((kc ^ (row & 7)) * 8);
        ldsoff[i] = c * 8;
    }

    short* A0 = &As[0][0]; short* A1b = &As[1][0];
    short* B0 = &Bs[0][0]; short* B1b = &Bs[1][0];

    f32x4 acc[8][4];
    #pragma unroll
    for (int m = 0; m < 8; m++)
        #pragma unroll
        for (int n = 0; n < 4; n++) acc[m][n] = (f32x4){0.f, 0.f, 0.f, 0.f};

    float4 xrL[4], xrH[4];   // X windows: xrL = lo-half, xrH = hi-half

    // ---- prologue: A(0) via reg+write; B(0); B-hi(1); xrL <- lo(1) ----
    XLOAD(xrL, 0, 0);
    XLOAD(xrH, 1, 0);
    stage_half_B(Mt, bcol, 0, 0, B0, goff, ldsoff);
    stage_half_B(Mt, bcol, 1, 0, B0, goff, ldsoff);
    stage_half_B(Mt, bcol, 1, 1, B1b, goff, ldsoff);
    XWRITE(A0, xrL);            // implicit vmcnt drains X(0) loads
    XWRITE(A0 + 8192, xrH);
    XLOAD(xrL, 0, 1);           // lo(1), written at ph3(0)
    // outstanding: [B(0):4, B-hi(1):2, xrL:4]; need B(0) -> vmcnt(6);
    // lgkmcnt(0) publishes A0 writes.
    asm volatile("s_waitcnt vmcnt(6) lgkmcnt(0)" ::: "memory");
    __builtin_amdgcn_s_barrier();

    short8 af[4][2], bfL[2][2], bfH[2][2];

    #pragma unroll 1
    for (int t = 0; t < NT - 1; t++) {
        const int cur = t & 1;
        short* Acur  = cur ? A1b : A0;
        short* Bcur  = cur ? B1b : B0;
        short* Anext = cur ? A0 : A1b;   // buf of t+1
        short* Bnext = cur ? B0 : B1b;

        // ---- ph1: quadrant (0,0); issue X-hi(t+1) (3-phase lead to ph4)
        LOAD_A(0); LOAD_B_TO(bfL, 0);
        if (t + 1 < NT) XLOAD(xrH, 1, (t + 1));
        __builtin_amdgcn_s_barrier();
        __builtin_amdgcn_s_setprio(1);
        MFMA_P(0, 0, bfL);
        __builtin_amdgcn_s_setprio(0);

        // ---- ph2: quadrant (0,1); DMA B-lo(t+1)
        LOAD_B_TO(bfH, 1);
        if (t + 1 < NT) stage_half_B(Mt, bcol, 0, t + 1, Bnext, goff, ldsoff);
        __builtin_amdgcn_s_barrier();
        __builtin_amdgcn_s_setprio(1);
        MFMA_P(0, 1, bfH);
        __builtin_amdgcn_s_setprio(0);

        // ---- ph3: quadrant (1,1); write A-lo(t+1) from xrL (issued ph4(t-1))
        LOAD_A(1);
        if (t + 1 < NT) XWRITE(Anext, xrL);   // implicit vmcnt(2): leaves B-lo
        __builtin_amdgcn_s_barrier();
        __builtin_amdgcn_s_setprio(1);
        MFMA_P(1, 1, bfH);
        __builtin_amdgcn_s_setprio(0);

        // ---- ph4: quadrant (1,0) [read-free: bfL persists];
        //      write A-hi(t+1) from xrH (issued ph1(t)); issue X-lo(t+2);
        //      DMA B-hi(t+2) into cur freed slot
        if (t + 1 < NT) XWRITE(Anext + 8192, xrH);  // implicit vmcnt(2): drains xrH
        if (t + 2 < NT) {
            XLOAD(xrL, 0, (t + 2));                 // 3-phase lead to ph3(t+1)
            stage_half_B(Mt, bcol, 1, t + 2, Bcur, goff, ldsoff);
        }
        // outstanding: [B-lo(t+1):2, xrL(t+2):4, B-hi(t+2):2] = 8;
        // vmcnt(6) drains B-lo(t+1); lgkmcnt(0) publishes both A-half writes.
        if (t + 2 < NT)      asm volatile("s_waitcnt vmcnt(6) lgkmcnt(0)" ::: "memory");
        else if (t + 1 < NT) asm volatile("s_waitcnt vmcnt(0) lgkmcnt(0)" ::: "memory");
        __builtin_amdgcn_s_barrier();
        __builtin_amdgcn_s_setprio(1);
        MFMA_P(1, 0, bfL);
        __builtin_amdgcn_s_setprio(0);
    }

    // ---- peeled tile NT-1 (cur=1): all data resident; distribute C stores ----
    {
        short* Acur = A1b;
        short* Bcur = B1b;

        // ph1: quadrant (0,0) -> store it
        LOAD_A(0); LOAD_B_TO(bfL, 0);
        __builtin_amdgcn_s_setprio(1);
        MFMA_P(0, 0, bfL);
        __builtin_amdgcn_s_setprio(0);
        STORE_Q(0, 0);

        // ph2: quadrant (0,1) -> store it
        LOAD_B_TO(bfH, 1);
        __builtin_amdgcn_s_setprio(1);
        MFMA_P(0, 1, bfH);
        __builtin_amdgcn_s_setprio(0);
        STORE_Q(0, 1);

        // ph3: quadrant (1,1) -> store it
        LOAD_A(1);
        __builtin_amdgcn_s_setprio(1);
        MFMA_P(1, 1, bfH);
        __builtin_amdgcn_s_setprio(0);
        STORE_Q(1, 1);

        // ph4: quadrant (1,0) -> store it
        __builtin_amdgcn_s_setprio(1);
        MFMA_P(1, 0, bfL);
        __builtin_amdgcn_s_setprio(0);
        STORE_Q(1, 0);
    }
}

extern "C" void kernel_launch(void* const* d_in, const int* in_sizes, int n_in,
                              void* d_out, int out_size, void* d_ws, size_t ws_size,
                              hipStream_t stream) {
    const float* X  = (const float*)d_in[0];  // [16384,1024]
    const float* AR = (const float*)d_in[1];
    const float* AI = (const float*)d_in[2];
    const float* H  = (const float*)d_in[3];
    const float* P  = (const float*)d_in[4];  // [8,1024,1024]
    float* out = (float*)d_out;

    char* ws = (char*)d_ws;
    float* w  = (float*)ws;                       // 32 KB
    short* Mt = (short*)(ws + 32768);             // 2 MB  (bf16 M^T)

    k_amps<<<1, 1024, 0, stream>>>(AR, AI, H, out, w);
    k_project_t<<<256, 256, 0, stream>>>(P, w, Mt);
    k_gemm_jit3<<<(NBATCH / 256) * (HD / 256), 512, 0, stream>>>(X, Mt, out);
}

// Round 21
// 63.884 us; speedup vs baseline: 1.1872x; 1.0872x over previous
//
#include <hip/hip_runtime.h>
#include <hip/hip_bf16.h>

#define NSTATES 8
#define HD      1024
#define NBATCH  16384
#define NT      16      // K-tiles of 64

// output layout (flat fp32, return order)
#define OUT_MEAS 0
#define OUT_CP   16777216
#define OUT_ENT  16777224
#define OUT_COH  16777225
#define OUT_AD   16777226
#define OUT_PH   16785418

typedef __attribute__((ext_vector_type(8))) short short8;
typedef __attribute__((ext_vector_type(4))) float f32x4;

__device__ __forceinline__ short f2bf(float f) {
    union { float f; unsigned u; } x; x.f = f;
    unsigned r = x.u + 0x7fffu + ((x.u >> 16) & 1u);  // RNE
    return (short)(r >> 16);
}

__device__ __forceinline__ unsigned cvtpk(float lo, float hi) {
    unsigned r;
    asm("v_cvt_pk_bf16_f32 %0, %1, %2" : "=v"(r) : "v"(lo), "v"(hi));
    return r;
}

__device__ __forceinline__ short8 pack8pk(float4 a, float4 b) {
    union { unsigned u[4]; short8 s; } r;
    r.u[0] = cvtpk(a.x, a.y);
    r.u[1] = cvtpk(a.z, a.w);
    r.u[2] = cvtpk(b.x, b.y);
    r.u[3] = cvtpk(b.z, b.w);
    return r.s;
}

// ---------------- K1: amplitude pipeline (1 block, 1024 threads) ----------------
__global__ __launch_bounds__(1024) void k_amps(const float* __restrict__ AR,
                                               const float* __restrict__ AI,
                                               const float* __restrict__ H,
                                               float* __restrict__ out,
                                               float* __restrict__ w) {
    __shared__ float redA[16 * NSTATES];
    __shared__ float redB[16 * 10];
    __shared__ float norms[NSTATES];
    __shared__ float sA[8][8], sA2[8][8], sA3[8][8];
    __shared__ float Ur[8][8], Ui[8][8];
    __shared__ float lamsa[2];

    const int tid = threadIdx.x;
    const int lane = tid & 63, wid = tid >> 6;
    const int d = tid;

    float arv[NSTATES], aiv[NSTATES];
    #pragma unroll
    for (int s = 0; s < NSTATES; s++) {
        arv[s] = AR[s * HD + d];
        aiv[s] = AI[s * HD + d];
    }
    float p[NSTATES];
    #pragma unroll
    for (int s = 0; s < NSTATES; s++) p[s] = arv[s] * arv[s] + aiv[s] * aiv[s];
    #pragma unroll
    for (int s = 0; s < NSTATES; s++)
        #pragma unroll
        for (int o = 32; o > 0; o >>= 1) p[s] += __shfl_down(p[s], o, 64);
    if (lane == 0)
        #pragma unroll
        for (int s = 0; s < NSTATES; s++) redA[wid * NSTATES + s] = p[s];
    if (tid < 64) {
        int i = tid >> 3, j = tid & 7;
        sA[i][j] = 0.5f * (H[i * 8 + j] + H[j * 8 + i]) * 0.01f;  // DT/PLANCK
    }
    __syncthreads();
    if (tid < 8) {
        float acc = 0.f;
        #pragma unroll
        for (int v = 0; v < 16; v++) acc += redA[v * NSTATES + tid];
        norms[tid] = acc;
    }
    if (tid < 64) {
        int i = tid >> 3, j = tid & 7;
        float acc = 0.f;
        #pragma unroll
        for (int k = 0; k < 8; k++) acc += sA[i][k] * sA[k][j];
        sA2[i][j] = acc;
    }
    __syncthreads();
    if (tid < 64) {
        int i = tid >> 3, j = tid & 7;
        float acc = 0.f;
        #pragma unroll
        for (int k = 0; k < 8; k++) acc += sA2[i][k] * sA[k][j];
        sA3[i][j] = acc;
        Ur[i][j] = ((i == j) ? 1.f : 0.f) - 0.5f * sA2[i][j];   // cos(A)
        Ui[i][j] = -(sA[i][j] - sA3[i][j] * (1.f / 6.f));       // -sin(A)
    }
    __syncthreads();

    #pragma unroll
    for (int s = 0; s < NSTATES; s++) {
        float inv = 1.0f / sqrtf(norms[s] + 1e-8f);
        arv[s] *= inv;
        aiv[s] *= inv;
    }
    float nr[NSTATES], ni[NSTATES];
    #pragma unroll
    for (int s = 0; s < NSTATES; s++) {
        float xr = 0.f, xi = 0.f;
        #pragma unroll
        for (int t = 0; t < NSTATES; t++) {
            float ur = Ur[s][t], ui = Ui[s][t];
            xr += ur * arv[t] - ui * aiv[t];
            xi += ur * aiv[t] + ui * arv[t];
        }
        nr[s] = xr; ni[s] = xi;
    }
    float dist[NSTATES], csum = 0.f, sabs = 0.f;
    #pragma unroll
    for (int s = 0; s < NSTATES; s++) {
        dist[s] = nr[s] * nr[s] + ni[s] * ni[s];
        csum += dist[s];
        sabs += sqrtf(dist[s]);
    }
    #pragma unroll
    for (int s = 0; s < NSTATES; s++) {
        out[OUT_AD + s * HD + d] = dist[s];
        out[OUT_PH + s * HD + d] = atan2f(ni[s], nr[s]);
        w[s * HD + d] = nr[s];
    }
    float cinv = 1.0f / (csum + 1e-8f);
    float q[10];
    #pragma unroll
    for (int s = 0; s < NSTATES; s++) q[s] = dist[s] * cinv;
    q[8] = csum; q[9] = sabs;
    #pragma unroll
    for (int v = 0; v < 10; v++)
        #pragma unroll
        for (int o = 32; o > 0; o >>= 1) q[v] += __shfl_down(q[v], o, 64);
    if (lane == 0)
        #pragma unroll
        for (int v = 0; v < 10; v++) redB[wid * 10 + v] = q[v];
    __syncthreads();
    if (tid < 10) {
        float acc = 0.f;
        #pragma unroll
        for (int v = 0; v < 16; v++) acc += redB[v * 10 + tid];
        if (tid < 8)       out[OUT_CP + tid] = acc * (1.0f / HD);
        else               lamsa[tid - 8] = acc;
    }
    __syncthreads();
    if (tid == 0) {
        float lam = lamsa[0], sa = lamsa[1];
        out[OUT_ENT] = -(lam * logf(lam + 1e-12f));
        out[OUT_COH] = sa * sa - lam;
    }
}

// ------- K3: fused project + transpose: Mt[e,d] = bf16( sum_s w[s,e]*P[s,d,e] ) -
__global__ __launch_bounds__(256) void k_project_t(const float* __restrict__ P,
                                                   const float* __restrict__ w,
                                                   short* __restrict__ Mt) {
    __shared__ float tile[64][65];
    int d0 = (blockIdx.x >> 4) * 64;
    int e0 = (blockIdx.x & 15) * 64;
    int tx = threadIdx.x & 63, ty = threadIdx.x >> 6;
    float wv[NSTATES];
    #pragma unroll
    for (int s = 0; s < NSTATES; s++) wv[s] = w[s * HD + e0 + tx];
    #pragma unroll
    for (int j = 0; j < 16; j++) {
        int r = ty + 4 * j;
        float acc = 0.f;
        #pragma unroll
        for (int s = 0; s < NSTATES; s++)
            acc += wv[s] * P[(size_t)s * HD * HD + (size_t)(d0 + r) * HD + e0 + tx];
        tile[r][tx] = acc;
    }
    __syncthreads();
    #pragma unroll
    for (int j = 0; j < 16; j++) {
        int er = ty + 4 * j;
        Mt[(size_t)(e0 + er) * HD + d0 + tx] = f2bf(tile[tx][er]);
    }
}

// -------- K4: out = bf16(X) @ Mt^T -- JIT-A, MERGED 2-phase tiles --------------
// 512 threads = 8 waves. vs R17: quadrant pairs merged -> 2 barriers/tile with
// 32 MFMA each (was 4 barriers x 16 MFMA). Staging layout:
//   P1(t): ds_reads A-lo,B-lo,B-hi; issue xrH(t+1); DMA B-lo(t+1)+B-hi(t+1);
//          barrier; MFMA q(0,0),(0,1).
//   P2(t): ds_reads A-hi; XWRITE A-lo/hi(t+1) (from xrL/xrH); issue xrL(t+2);
//          vmcnt(4)+lgkm(0); barrier; MFMA q(1,1),(1,0).
// Hazard audit (write safe iff last lgkm-consumption precedes a barrier the
// writer passed): A-lo(t+1) target last consumed t-1 P1-MFMA (2 barriers back);
// A-hi target last consumed t-1 P2-MFMA (1 barrier back + explicit lgkm drain);
// B(t+1) targets last consumed t-1 P1/P2 MFMA (>=1 barrier back). B-hi stage
// deliberately moved OUT of P2 (would have 0-barrier slack vs t-P1 bfH reads).
// FIFO: enter P1(t): [xrL(t+1):4]; P1 adds xrH:4+B(t+1):4; XWRITE-lo implicit
// vmcnt(8), XWRITE-hi vmcnt(4); end-of-tile vmcnt(4) drains B(t+1), keeps
// xrL(t+2); t=NT-2 -> vmcnt(0). Peeled last tile with distributed C stores.

__device__ __forceinline__ void stage_half_B(const short* __restrict__ srcBase,
                                             int rowbase, int h, int t2,
                                             short* dst, const int* goff,
                                             const int* ldsoff) {
    #pragma unroll
    for (int i = 0; i < 2; i++) {
        const short* g = srcBase + (size_t)(rowbase + h * 128) * HD + t2 * 64 + goff[i];
        __builtin_amdgcn_global_load_lds(
            (const __attribute__((address_space(1))) void*)g,
            (__attribute__((address_space(3))) void*)(dst + h * 8192 + ldsoff[i]),
            16, 0, 0);
    }
}

#define XLOAD(dst, h, t2)                                                      \
    {                                                                          \
        const float* b_ = X + (size_t)(brow + (h) * 128) * HD + (t2) * 64;     \
        dst[0] = *reinterpret_cast<const float4*>(b_ + goff[0]);               \
        dst[1] = *reinterpret_cast<const float4*>(b_ + goff[0] + 4);           \
        dst[2] = *reinterpret_cast<const float4*>(b_ + goff[1]);               \
        dst[3] = *reinterpret_cast<const float4*>(b_ + goff[1] + 4);           \
    }

#define XWRITE(dstlds, src)                                                    \
    {                                                                          \
        *reinterpret_cast<short8*>((dstlds) + ldsoff[0]) = pack8pk(src[0], src[1]); \
        *reinterpret_cast<short8*>((dstlds) + ldsoff[1]) = pack8pk(src[2], src[3]); \
    }

#define LOAD_A(qa)                                                             \
    _Pragma("unroll") for (int mf = 0; mf < 4; mf++)                           \
    _Pragma("unroll") for (int kk = 0; kk < 2; kk++)                           \
        af[mf][kk] = *reinterpret_cast<const short8*>(                         \
            &Acur[((qa) * 128 + wr64 + mf * 16 + ln15) * 64 + kx[kk]]);

#define LOAD_B_TO(dst, qb)                                                     \
    _Pragma("unroll") for (int nf = 0; nf < 2; nf++)                           \
    _Pragma("unroll") for (int kk = 0; kk < 2; kk++)                           \
        dst[nf][kk] = *reinterpret_cast<const short8*>(                        \
            &Bcur[((qb) * 128 + wn32 + nf * 16 + ln15) * 64 + kx[kk]]);

#define MFMA_P(qa, qb, breg)                                                   \
    _Pragma("unroll") for (int mf = 0; mf < 4; mf++)                           \
    _Pragma("unroll") for (int nf = 0; nf < 2; nf++)                           \
    _Pragma("unroll") for (int kk = 0; kk < 2; kk++)                           \
        acc[(qa) * 4 + mf][(qb) * 2 + nf] =                                    \
            __builtin_amdgcn_mfma_f32_16x16x32_bf16(                           \
                af[mf][kk], breg[nf][kk], acc[(qa) * 4 + mf][(qb) * 2 + nf], 0, 0, 0);

// store one C-quadrant (C/D layout col=lane&15, row=(lane>>4)*4+j  [m89])
#define STORE_Q(qa, qb)                                                        \
    _Pragma("unroll") for (int mf = 0; mf < 4; mf++)                           \
    _Pragma("unroll") for (int nf = 0; nf < 2; nf++)                           \
    _Pragma("unroll") for (int j = 0; j < 4; j++) {                            \
        int r = brow + (qa) * 128 + wr64 + mf * 16 + l16 * 4 + j;              \
        int c = bcol + (qb) * 128 + wn32 + nf * 16 + ln15;                     \
        out[(size_t)r * HD + c] = acc[(qa) * 4 + mf][(qb) * 2 + nf][j];        \
    }

__global__ __launch_bounds__(512, 1) void k_gemm_2ph(const float* __restrict__ X,
                                                     const short* __restrict__ Mt,
                                                     float* __restrict__ out) {
    __shared__ short As[2][256 * 64];   // 64 KiB: [buf][half*128+row][kchunk]
    __shared__ short Bs[2][256 * 64];   // 64 KiB

    const int bid = blockIdx.x;                       // 256 blocks (64 bm x 4 bn)
    const int swz = (bid & 7) * 32 + (bid >> 3);      // XCD-contiguous, bijective
    const int brow = (swz >> 2) * 256;
    const int bcol = (swz & 3) * 256;

    const int tid  = threadIdx.x;
    const int lane = tid & 63, wid = tid >> 6;
    const int wr = wid >> 2, wn = wid & 3;
    const int ln15 = lane & 15, l16 = lane >> 4;
    const int wr64 = wr * 64;
    const int wn32 = wn * 32;

    // ds_read swizzled k-chunk offsets (shorts): chunk = kg ^ (row&7); row&7==ln15&7
    int kx[2];
    kx[0] = ((l16 + 0) ^ (ln15 & 7)) * 8;
    kx[1] = ((l16 + 4) ^ (ln15 & 7)) * 8;

    // staging offsets (elements): LDS linear dest, inverse-swizzled global source
    int goff[2], ldsoff[2];
    #pragma unroll
    for (int i = 0; i < 2; i++) {
        int c = tid + 512 * i;
        int row = c >> 3, kc = c & 7;
        goff[i]   = row * HD + ((kc ^ (row & 7)) * 8);
        ldsoff[i] = c * 8;
    }

    short* A0 = &As[0][0]; short* A1b = &As[1][0];
    short* B0 = &Bs[0][0]; short* B1b = &Bs[1][0];

    f32x4 acc[8][4];
    #pragma unroll
    for (int m = 0; m < 8; m++)
        #pragma unroll
        for (int n = 0; n < 4; n++) acc[m][n] = (f32x4){0.f, 0.f, 0.f, 0.f};

    float4 xrL[4], xrH[4];   // X windows: xrL = lo-half, xrH = hi-half

    // ---- prologue: A(0) via reg+write; B(0) lo+hi; xrL <- lo(1) ----
    XLOAD(xrL, 0, 0);
    XLOAD(xrH, 1, 0);
    stage_half_B(Mt, bcol, 0, 0, B0, goff, ldsoff);
    stage_half_B(Mt, bcol, 1, 0, B0, goff, ldsoff);
    XWRITE(A0, xrL);            // implicit vmcnt(8): drains X(0)-lo
    XWRITE(A0 + 8192, xrH);     // implicit vmcnt(4): drains X(0)-hi, keeps B(0)
    XLOAD(xrL, 0, 1);           // lo(1), written at P2(0)
    // outstanding: [B(0):4, xrL(1):4]; need B(0) -> vmcnt(4); lgkm publishes A0.
    asm volatile("s_waitcnt vmcnt(4) lgkmcnt(0)" ::: "memory");
    __builtin_amdgcn_s_barrier();

    short8 af[4][2], bfL[2][2], bfH[2][2];

    #pragma unroll 1
    for (int t = 0; t < NT - 1; t++) {
        const int cur = t & 1;
        short* Acur  = cur ? A1b : A0;
        short* Bcur  = cur ? B1b : B0;
        short* Anext = cur ? A0 : A1b;   // buf of t+1
        short* Bnext = cur ? B0 : B1b;

        // ---- P1: quadrants (0,0)+(0,1); issue xrH(t+1); DMA B(t+1) lo+hi
        LOAD_A(0); LOAD_B_TO(bfL, 0); LOAD_B_TO(bfH, 1);
        XLOAD(xrH, 1, (t + 1));
        stage_half_B(Mt, bcol, 0, t + 1, Bnext, goff, ldsoff);
        stage_half_B(Mt, bcol, 1, t + 1, Bnext, goff, ldsoff);
        __builtin_amdgcn_s_barrier();
        __builtin_amdgcn_s_setprio(1);
        MFMA_P(0, 0, bfL);
        MFMA_P(0, 1, bfH);
        __builtin_amdgcn_s_setprio(0);

        // ---- P2: quadrants (1,1)+(1,0); write A(t+1); issue xrL(t+2)
        LOAD_A(1);
        XWRITE(Anext, xrL);          // implicit vmcnt(8): drains xrL(t+1)
        XWRITE(Anext + 8192, xrH);   // implicit vmcnt(4): drains xrH(t+1)
        if (t + 2 < NT) XLOAD(xrL, 0, (t + 2));
        // outstanding: [B(t+1):4 (, xrL(t+2):4)]; drain B(t+1); publish A writes.
        if (t + 2 < NT) asm volatile("s_waitcnt vmcnt(4) lgkmcnt(0)" ::: "memory");
        else            asm volatile("s_waitcnt vmcnt(0) lgkmcnt(0)" ::: "memory");
        __builtin_amdgcn_s_barrier();
        __builtin_amdgcn_s_setprio(1);
        MFMA_P(1, 1, bfH);
        MFMA_P(1, 0, bfL);
        __builtin_amdgcn_s_setprio(0);
    }

    // ---- peeled tile NT-1 (cur=1): all data resident; distribute C stores ----
    {
        short* Acur = A1b;
        short* Bcur = B1b;

        LOAD_A(0); LOAD_B_TO(bfL, 0); LOAD_B_TO(bfH, 1);
        __builtin_amdgcn_s_setprio(1);
        MFMA_P(0, 0, bfL);
        __builtin_amdgcn_s_setprio(0);
        STORE_Q(0, 0);

        __builtin_amdgcn_s_setprio(1);
        MFMA_P(0, 1, bfH);
        __builtin_amdgcn_s_setprio(0);
        STORE_Q(0, 1);

        LOAD_A(1);
        __builtin_amdgcn_s_setprio(1);
        MFMA_P(1, 1, bfH);
        __builtin_amdgcn_s_setprio(0);
        STORE_Q(1, 1);

        __builtin_amdgcn_s_setprio(1);
        MFMA_P(1, 0, bfL);
        __builtin_amdgcn_s_setprio(0);
        STORE_Q(1, 0);
    }
}

extern "C" void kernel_launch(void* const* d_in, const int* in_sizes, int n_in,
                              void* d_out, int out_size, void* d_ws, size_t ws_size,
                              hipStream_t stream) {
    const float* X  = (const float*)d_in[0];  // [16384,1024]
    const float* AR = (const float*)d_in[1];
    const float* AI = (const float*)d_in[2];
    const float* H  = (const float*)d_in[3];
    const float* P  = (const float*)d_in[4];  // [8,1024,1024]
    float* out = (float*)d_out;

    char* ws = (char*)d_ws;
    float* w  = (float*)ws;                       // 32 KB
    short* Mt = (short*)(ws + 32768);             // 2 MB  (bf16 M^T)

    k_amps<<<1, 1024, 0, stream>>>(AR, AI, H, out, w);
    k_project_t<<<256, 256, 0, stream>>>(P, w, Mt);
    k_gemm_2ph<<<(NBATCH / 256) * (HD / 256), 512, 0, stream>>>(X, Mt, out);
}